// Round 7
// baseline (541.585 us; speedup 1.0000x reference)
//
#include <hip/hip_runtime.h>
#include <hip/hip_bf16.h>

// Problem constants
#define T_TOKENS 4096      // B*S
#define DIM      1024
#define HID      4096
#define NE       8
#define CAP      4096      // max tokens per expert
#define SPLITS   2         // split-K factor for ffn2
#define KSP      (HID / SPLITS)   // 2048

typedef __attribute__((ext_vector_type(8))) short  bf16x8;
typedef __attribute__((ext_vector_type(4))) float  f32x4;
typedef __attribute__((ext_vector_type(4))) ushort u16x4;

__device__ static inline ushort f2bf(float f) {
    __hip_bfloat16 h = __float2bfloat16(f);
    return *(ushort*)&h;
}

// async global -> LDS, 16 bytes per lane. LDS dest = wave-uniform base +
// lane*16 (linear). Swizzle applied on the GLOBAL source address.
__device__ static inline void gll16(const void* g, void* l) {
    __builtin_amdgcn_global_load_lds(
        (const __attribute__((address_space(1))) void*)g,
        (__attribute__((address_space(3))) void*)l,
        16, 0, 0);
}

#define MFMA16(a, b, c) __builtin_amdgcn_mfma_f32_16x16x32_bf16((a), (b), (c), 0, 0, 0)

// ---------------------------------------------------------------------------
// Gate: logits -> top2 -> softmax -> per-expert token lists; also x -> bf16.
// ---------------------------------------------------------------------------
__global__ __launch_bounds__(64) void gate_kernel(
    const float* __restrict__ x, const float* __restrict__ gw,
    const float* __restrict__ gb, __hip_bfloat16* __restrict__ xb,
    int* __restrict__ counts, int* __restrict__ tlist, float* __restrict__ plist)
{
    const int tok = blockIdx.x;
    const int l   = threadIdx.x;
    const float* xr = x + (size_t)tok * DIM;

    float part[NE];
#pragma unroll
    for (int e = 0; e < NE; e++) part[e] = 0.f;

#pragma unroll
    for (int i = 0; i < DIM / 64; i++) {
        int d = i * 64 + l;
        float xv = xr[d];
        xb[(size_t)tok * DIM + d] = __float2bfloat16(xv);
        const float4* g4 = (const float4*)(gw + (size_t)d * NE);
        float4 a = g4[0], b = g4[1];
        part[0] += xv * a.x; part[1] += xv * a.y;
        part[2] += xv * a.z; part[3] += xv * a.w;
        part[4] += xv * b.x; part[5] += xv * b.y;
        part[6] += xv * b.z; part[7] += xv * b.w;
    }
#pragma unroll
    for (int off = 32; off > 0; off >>= 1) {
#pragma unroll
        for (int e = 0; e < NE; e++) part[e] += __shfl_xor(part[e], off, 64);
    }
    if (l == 0) {
        float lg[NE];
#pragma unroll
        for (int e = 0; e < NE; e++) lg[e] = part[e] + gb[e];
        int i0 = 0;
#pragma unroll
        for (int e = 1; e < NE; e++) if (lg[e] > lg[i0]) i0 = e;   // lowest idx on tie
        int i1 = (i0 == 0) ? 1 : 0;
#pragma unroll
        for (int e = 0; e < NE; e++) if (e != i0 && lg[e] > lg[i1]) i1 = e;
        float t  = expf(lg[i1] - lg[i0]);
        float p0 = 1.f / (1.f + t);
        float p1 = t / (1.f + t);
        int pos0 = atomicAdd(&counts[i0], 1);
        tlist[i0 * CAP + pos0] = tok; plist[i0 * CAP + pos0] = p0;
        int pos1 = atomicAdd(&counts[i1], 1);
        tlist[i1 * CAP + pos1] = tok; plist[i1 * CAP + pos1] = p1;
    }
}

// ---------------------------------------------------------------------------
// finalize: prefix-sum bases + build persistent task lists from counts.
// task1 (ffn1): (e<<16)|(rb<<8)|cb   cb 0..15  (rb-major within expert)
// task2 (ffn2): (e<<16)|(rb<<8)|(cb*2+sp)      cb 0..3, sp 0..1
// ---------------------------------------------------------------------------
__global__ void finalize_kernel(const int* __restrict__ counts, int* __restrict__ base,
                                int* __restrict__ task1, int* __restrict__ task2,
                                int* __restrict__ ntasks)
{
    __shared__ int stc[NE], so1[NE], so2[NE];
    if (threadIdx.x == 0) {
        int acc = 0, o1 = 0, o2 = 0;
        for (int e = 0; e < NE; e++) {
            base[e] = acc; acc += counts[e];
            int tc = (counts[e] + 255) >> 8;
            stc[e] = tc; so1[e] = o1; so2[e] = o2;
            o1 += tc * 16; o2 += tc * 8;
        }
        base[NE] = acc;
        ntasks[0] = o1; ntasks[1] = o2;
    }
    __syncthreads();
    for (int e = 0; e < NE; e++) {
        int tc = stc[e];
        for (int i = threadIdx.x; i < tc * 16; i += 64) {
            int rb = i >> 4, cb = i & 15;
            task1[so1[e] + i] = (e << 16) | (rb << 8) | cb;
        }
        for (int i = threadIdx.x; i < tc * 8; i += 64) {
            int rb = i >> 3, c = i & 7;
            task2[so2[e] + i] = (e << 16) | (rb << 8) | c;
        }
    }
}

// ---------------------------------------------------------------------------
// Transpose + f32->bf16 convert:  in [E][K][N] f32  ->  out [E][N][K] bf16
// ---------------------------------------------------------------------------
__global__ __launch_bounds__(256) void transpose_cvt64(
    const float* __restrict__ in, __hip_bfloat16* __restrict__ outp, int K, int N)
{
    __shared__ ushort tile[64][68];
    const int e  = blockIdx.z;
    const float* src = in + (size_t)e * K * N;
    ushort* dst = (ushort*)outp + (size_t)e * K * N;
    const int k0 = blockIdx.y * 64, n0 = blockIdx.x * 64;
    const int tid = threadIdx.x;

    const int rn4 = (tid & 15) * 4;
    const int rk  = tid >> 4;
#pragma unroll
    for (int p = 0; p < 4; p++) {
        int k = rk + p * 16;
        float4 v = *(const float4*)&src[(size_t)(k0 + k) * N + n0 + rn4];
        tile[k][rn4 + 0] = f2bf(v.x);
        tile[k][rn4 + 1] = f2bf(v.y);
        tile[k][rn4 + 2] = f2bf(v.z);
        tile[k][rn4 + 3] = f2bf(v.w);
    }
    __syncthreads();
    const int wk4 = (tid & 15) * 4;
    const int wn  = tid >> 4;
#pragma unroll
    for (int p = 0; p < 4; p++) {
        int n = wn + p * 16;
        u16x4 u;
        u[0] = tile[wk4 + 0][n];
        u[1] = tile[wk4 + 1][n];
        u[2] = tile[wk4 + 2][n];
        u[3] = tile[wk4 + 3][n];
        *(u16x4*)&dst[(size_t)(n0 + n) * K + k0 + wk4] = u;
    }
}

// ===========================================================================
// 256x256 8-phase grouped GEMM core (BM=BN=256, BK=64, 8 waves 2Mx4N).
// LDS 128 KiB: A slots [dbuf][khalf] 16KB each at (d*2+s)*8192 ushorts,
// B slots at 32768 + (d*2+s)*8192. Slot interior: [256 rows][4 chunks of 8
// bf16], chunk stored at c ^ ((row>>1)&3)  (measured 0 bank conflicts).
// Pipeline: compute tile t (dbuf t&1) while t+1 fully staged and t+2
// arriving. Stage issues: P0:(t+1).Bk1, P1:(t+2).Ak0, P2:(t+2).Bk0,
// P3:(t+2).Ak1 — each targets a slot whose reads finished a barrier earlier.
// One counted wait per tile: vmcnt(6) lands ALL of tile t+1 before barrier.
// ===========================================================================

#define AOFFc(d,s) (((d)*2+(s))*8192)
#define BOFFc(d,s) (32768 + ((d)*2+(s))*8192)

// per-phase MFMA cluster: 8 mi x 2 nj
#define MFMA_CL(nj0, nj1)                                                    \
    _Pragma("unroll")                                                        \
    for (int mi = 0; mi < 8; mi++) {                                         \
        acc[mi][nj0] = MFMA16(af[mi], bf##nj0, acc[mi][nj0]);                \
        acc[mi][nj1] = MFMA16(af[mi], bf##nj1, acc[mi][nj1]);                \
    }

#define GEMM_CORE(NT, srcA0, srcA1, srcB0, srcB1)                            \
    f32x4 acc[8][4];                                                         \
    _Pragma("unroll")                                                        \
    for (int i = 0; i < 8; i++)                                              \
        _Pragma("unroll")                                                    \
        for (int j = 0; j < 4; j++) acc[i][j] = (f32x4){0.f,0.f,0.f,0.f};    \
    const int a0 = (wr * 128 + lm) * 32 + rch;                               \
    const int b0 = (wc * 64 + lm) * 32 + rch;                                \
    /* prologue: tile0 all 4 halves, then tile1 first 3 halves */            \
    gll16(srcA0,      &lds[AOFFc(0,0) + w*512]);                             \
    gll16(srcA1,      &lds[AOFFc(0,0) + 4096 + w*512]);                      \
    gll16(srcB0,      &lds[BOFFc(0,0) + w*512]);                             \
    gll16(srcB1,      &lds[BOFFc(0,0) + 4096 + w*512]);                      \
    gll16(srcA0 + 32, &lds[AOFFc(0,1) + w*512]);                             \
    gll16(srcA1 + 32, &lds[AOFFc(0,1) + 4096 + w*512]);                      \
    gll16(srcB0 + 32, &lds[BOFFc(0,1) + w*512]);                             \
    gll16(srcB1 + 32, &lds[BOFFc(0,1) + 4096 + w*512]);                      \
    asm volatile("s_waitcnt vmcnt(4)" ::: "memory");                         \
    gll16(srcA0 + 64, &lds[AOFFc(1,0) + w*512]);                             \
    gll16(srcA1 + 64, &lds[AOFFc(1,0) + 4096 + w*512]);                      \
    gll16(srcB0 + 64, &lds[BOFFc(1,0) + w*512]);                             \
    gll16(srcB1 + 64, &lds[BOFFc(1,0) + 4096 + w*512]);                      \
    gll16(srcA0 + 96, &lds[AOFFc(1,1) + w*512]);                             \
    gll16(srcA1 + 96, &lds[AOFFc(1,1) + 4096 + w*512]);                      \
    asm volatile("s_waitcnt vmcnt(6)" ::: "memory");                         \
    __builtin_amdgcn_s_barrier();                                            \
    _Pragma("unroll 1")                                                      \
    for (int t = 0; t < NT; t++) {                                           \
        const int d   = t & 1;                                               \
        const int aof  = d * 16384,        bof  = 32768 + d * 16384;         \
        const int aofN = (d^1) * 16384,    bofN = 32768 + (d^1) * 16384;     \
        bf16x8 af[8]; bf16x8 bf0, bf1, bf2, bf3;                             \
        /* ---- P0: A ksub0 + B nj0,1 ksub0; stage (t+1).B-k1 ---- */        \
        _Pragma("unroll")                                                    \
        for (int mi = 0; mi < 8; mi++)                                       \
            af[mi] = *(const bf16x8*)&lds[aof + a0 + mi*512];                \
        bf0 = *(const bf16x8*)&lds[bof + b0];                                \
        bf1 = *(const bf16x8*)&lds[bof + b0 + 512];                          \
        if (t + 1 < NT) {                                                    \
            size_t ko = (size_t)(t+1)*64 + 32;                               \
            gll16(srcB0 + ko, &lds[bofN + 8192 + w*512]);                    \
            gll16(srcB1 + ko, &lds[bofN + 8192 + 4096 + w*512]);             \
        }                                                                    \
        __builtin_amdgcn_s_barrier();                                        \
        __builtin_amdgcn_s_setprio(1);                                       \
        MFMA_CL(0, 1)                                                        \
        __builtin_amdgcn_s_setprio(0);                                       \
        __builtin_amdgcn_s_barrier();                                        \
        /* ---- P1: B nj2,3 ksub0; stage (t+2).A-k0 ---- */                  \
        bf2 = *(const bf16x8*)&lds[bof + b0 + 1024];                         \
        bf3 = *(const bf16x8*)&lds[bof + b0 + 1536];                         \
        if (t + 2 < NT) {                                                    \
            size_t ko = (size_t)(t+2)*64;                                    \
            gll16(srcA0 + ko, &lds[aof + w*512]);                            \
            gll16(srcA1 + ko, &lds[aof + 4096 + w*512]);                     \
        }                                                                    \
        __builtin_amdgcn_s_barrier();                                        \
        __builtin_amdgcn_s_setprio(1);                                       \
        MFMA_CL(2, 3)                                                        \
        __builtin_amdgcn_s_setprio(0);                                       \
        __builtin_amdgcn_s_barrier();                                        \
        /* ---- P2: A ksub1 + B nj0,1 ksub1; stage (t+2).B-k0 ---- */        \
        _Pragma("unroll")                                                    \
        for (int mi = 0; mi < 8; mi++)                                       \
            af[mi] = *(const bf16x8*)&lds[aof + 8192 + a0 + mi*512];         \
        bf0 = *(const bf16x8*)&lds[bof + 8192 + b0];                         \
        bf1 = *(const bf16x8*)&lds[bof + 8192 + b0 + 512];                   \
        if (t + 2 < NT) {                                                    \
            size_t ko = (size_t)(t+2)*64;                                    \
            gll16(srcB0 + ko, &lds[bof + w*512]);                            \
            gll16(srcB1 + ko, &lds[bof + 4096 + w*512]);                     \
        }                                                                    \
        __builtin_amdgcn_s_barrier();                                        \
        __builtin_amdgcn_s_setprio(1);                                       \
        MFMA_CL(0, 1)                                                        \
        __builtin_amdgcn_s_setprio(0);                                       \
        __builtin_amdgcn_s_barrier();                                        \
        /* ---- P3: B nj2,3 ksub1; stage (t+2).A-k1; counted wait ---- */    \
        bf2 = *(const bf16x8*)&lds[bof + 8192 + b0 + 1024];                  \
        bf3 = *(const bf16x8*)&lds[bof + 8192 + b0 + 1536];                  \
        if (t + 2 < NT) {                                                    \
            size_t ko = (size_t)(t+2)*64 + 32;                               \
            gll16(srcA0 + ko, &lds[aof + 8192 + w*512]);                     \
            gll16(srcA1 + ko, &lds[aof + 8192 + 4096 + w*512]);              \
        }                                                                    \
        __builtin_amdgcn_s_barrier();                                        \
        __builtin_amdgcn_s_setprio(1);                                       \
        MFMA_CL(2, 3)                                                        \
        __builtin_amdgcn_s_setprio(0);                                       \
        if (t < NT - 2) { asm volatile("s_waitcnt vmcnt(6)" ::: "memory"); } \
        else            { asm volatile("s_waitcnt vmcnt(0)" ::: "memory"); } \
        __builtin_amdgcn_s_barrier();                                        \
    }

// ---------------------------------------------------------------------------
// FFN pass 1 (persistent):  H = gelu( gather(xb) @ w1t^T + b1 )
// 256 resident blocks (1/CU, 128K LDS); dynamic ticket over task1 list.
// NOTE: __launch_bounds__(512, 1) — (512,2) demanded 4 waves/SIMD, capping
// VGPRs at 128 and spilling the 128-reg accumulator to scratch (R6: VGPR=108,
// MfmaUtil pinned at 15%). One 8-wave block per CU is the intended occupancy.
// ---------------------------------------------------------------------------
__global__ __launch_bounds__(512, 1) void ffn1_kernel(
    const __hip_bfloat16* __restrict__ xb, const __hip_bfloat16* __restrict__ w1t,
    const float* __restrict__ b1, const int* __restrict__ counts,
    const int* __restrict__ base, const int* __restrict__ tlist,
    const int* __restrict__ task1, const int* __restrict__ ntasks,
    int* __restrict__ ticket, __hip_bfloat16* __restrict__ H)
{
    __shared__ __align__(16) ushort lds[65536];   // 128 KiB
    __shared__ int s_task;

    const int tid = threadIdx.x;
    const int l = tid & 63, w = tid >> 6;
    const int wr = w >> 2, wc = w & 3;
    const int lm = l & 15, kg = l >> 4;
    const int rch = (kg ^ ((lm >> 1) & 3)) * 8;
    const int srow = tid >> 2;                    // 0..127
    const int sch  = tid & 3;
    const int sc0  = (sch ^ ((srow >> 1) & 3)) * 8;
    const int nt1  = ntasks[0];

    for (;;) {
        __syncthreads();                           // fences prev task's LDS use
        if (tid == 0) s_task = atomicAdd(ticket, 1);
        __syncthreads();
        const int task = s_task;
        if (task >= nt1) break;
        const int v  = task1[task];
        const int e  = v >> 16, rb = (v >> 8) & 255, cb = v & 255;
        const int ne = counts[e];

        const int rA0g = rb * 256 + srow;
        const int rA1g = rA0g + 128;
        const int tok0 = tlist[e * CAP + (rA0g < ne ? rA0g : ne - 1)];
        const int tok1 = tlist[e * CAP + (rA1g < ne ? rA1g : ne - 1)];
        const ushort* srcA0 = (const ushort*)xb + (size_t)tok0 * DIM + sc0;
        const ushort* srcA1 = (const ushort*)xb + (size_t)tok1 * DIM + sc0;
        const ushort* srcB0 = (const ushort*)w1t + ((size_t)e * HID + cb * 256 + srow) * DIM + sc0;
        const ushort* srcB1 = srcB0 + (size_t)128 * DIM;

        GEMM_CORE(16, srcA0, srcA1, srcB0, srcB1)

        // epilogue: bias + exact GELU -> bf16 H (grouped rows)
        const int hb = base[e];
#pragma unroll
        for (int nj = 0; nj < 4; nj++) {
            int col = cb * 256 + wc * 64 + nj * 16 + lm;
            float bias = b1[e * HID + col];
#pragma unroll
            for (int mi = 0; mi < 8; mi++) {
#pragma unroll
                for (int jj = 0; jj < 4; jj++) {
                    int r = rb * 256 + wr * 128 + mi * 16 + kg * 4 + jj;
                    if (r < ne) {
                        float vv = acc[mi][nj][jj] + bias;
                        vv = 0.5f * vv * (1.0f + erff(vv * 0.70710678118654752f));
                        H[(size_t)(hb + r) * HID + col] = __float2bfloat16(vv);
                    }
                }
            }
        }
    }
}

// ---------------------------------------------------------------------------
// FFN pass 2 (persistent, split-K=2):  out[token] += prob * ( H @ w2t^T + b2 )
// ---------------------------------------------------------------------------
__global__ __launch_bounds__(512, 1) void ffn2_kernel(
    const __hip_bfloat16* __restrict__ H, const __hip_bfloat16* __restrict__ w2t,
    const float* __restrict__ b2, const int* __restrict__ counts,
    const int* __restrict__ base, const int* __restrict__ tlist,
    const float* __restrict__ plist, const int* __restrict__ task2,
    const int* __restrict__ ntasks, int* __restrict__ ticket,
    float* __restrict__ out)
{
    __shared__ __align__(16) ushort lds[65536];   // 128 KiB
    __shared__ int s_task;

    const int tid = threadIdx.x;
    const int l = tid & 63, w = tid >> 6;
    const int wr = w >> 2, wc = w & 3;
    const int lm = l & 15, kg = l >> 4;
    const int rch = (kg ^ ((lm >> 1) & 3)) * 8;
    const int srow = tid >> 2;
    const int sch  = tid & 3;
    const int sc0  = (sch ^ ((srow >> 1) & 3)) * 8;
    const int nt2  = ntasks[1];

    for (;;) {
        __syncthreads();
        if (tid == 0) s_task = atomicAdd(ticket, 1);
        __syncthreads();
        const int task = s_task;
        if (task >= nt2) break;
        const int v  = task2[task];
        const int e  = v >> 16, rb = (v >> 8) & 255;
        const int cb = (v & 255) >> 1, sp = v & 1;
        const int ne = counts[e];
        const int hb = base[e];

        const int rA0g = rb * 256 + srow;
        const int rA1g = rA0g + 128;
        const int hr0  = hb + (rA0g < ne ? rA0g : ne - 1);
        const int hr1  = hb + (rA1g < ne ? rA1g : ne - 1);
        const size_t ko0 = (size_t)sp * KSP;
        const ushort* srcA0 = (const ushort*)H + (size_t)hr0 * HID + ko0 + sc0;
        const ushort* srcA1 = (const ushort*)H + (size_t)hr1 * HID + ko0 + sc0;
        const ushort* srcB0 = (const ushort*)w2t + ((size_t)e * DIM + cb * 256 + srow) * HID + ko0 + sc0;
        const ushort* srcB1 = srcB0 + (size_t)128 * HID;

        GEMM_CORE(32, srcA0, srcA1, srcB0, srcB1)

        // epilogue: prob-weighted atomic scatter to out (bias only on split 0)
#pragma unroll
        for (int mi = 0; mi < 8; mi++) {
#pragma unroll
            for (int jj = 0; jj < 4; jj++) {
                int r = rb * 256 + wr * 128 + mi * 16 + kg * 4 + jj;
                if (r < ne) {
                    int tok = tlist[e * CAP + r];
                    float p = plist[e * CAP + r];
                    float* orow = out + (size_t)tok * DIM;
#pragma unroll
                    for (int nj = 0; nj < 4; nj++) {
                        int col = cb * 256 + wc * 64 + nj * 16 + lm;
                        float vv = acc[mi][nj][jj];
                        if (sp == 0) vv += b2[e * DIM + col];
                        unsafeAtomicAdd(&orow[col], vv * p);
                    }
                }
            }
        }
    }
}

// ---------------------------------------------------------------------------
extern "C" void kernel_launch(void* const* d_in, const int* in_sizes, int n_in,
                              void* d_out, int out_size, void* d_ws, size_t ws_size,
                              hipStream_t stream)
{
    const float* x  = (const float*)d_in[0];
    const float* gw = (const float*)d_in[1];
    const float* gb = (const float*)d_in[2];
    const float* w1 = (const float*)d_in[3];
    const float* b1 = (const float*)d_in[4];
    const float* w2 = (const float*)d_in[5];
    const float* b2 = (const float*)d_in[6];
    float* out = (float*)d_out;

    // workspace carve (bytes)
    char* ws = (char*)d_ws;
    __hip_bfloat16* w1t = (__hip_bfloat16*)(ws);                    // 67108864
    __hip_bfloat16* w2t = (__hip_bfloat16*)(ws + 67108864);         // 67108864
    __hip_bfloat16* Hb  = (__hip_bfloat16*)(ws + 134217728);        // 67108864
    __hip_bfloat16* xb  = (__hip_bfloat16*)(ws + 201326592);        // 8388608
    int*   tlist  = (int*)  (ws + 209715200);                       // 131072
    float* plist  = (float*)(ws + 209846272);                       // 131072
    int*   counts = (int*)  (ws + 209977344);                       // 64
    int*   basep  = (int*)  (ws + 209977408);                       // 64
    int*   ntasks = (int*)  (ws + 209977472);                       // 64
    int*   tickets= (int*)  (ws + 209977536);                       // 64
    int*   task1  = (int*)  (ws + 209977600);                       // 8192
    int*   task2  = (int*)  (ws + 209985792);                       // 4096

    hipMemsetAsync(out, 0, (size_t)T_TOKENS * DIM * sizeof(float), stream);
    hipMemsetAsync(counts, 0, 256, stream);   // counts+basep+ntasks+tickets

    gate_kernel<<<T_TOKENS, 64, 0, stream>>>(x, gw, gb, xb, counts, tlist, plist);
    finalize_kernel<<<1, 64, 0, stream>>>(counts, basep, task1, task2, ntasks);

    transpose_cvt64<<<dim3(HID / 64, DIM / 64, NE), 256, 0, stream>>>(w1, w1t, DIM, HID);
    transpose_cvt64<<<dim3(DIM / 64, HID / 64, NE), 256, 0, stream>>>(w2, w2t, HID, DIM);

    // persistent grids: 1 block per CU, dynamic ticket scheduling
    ffn1_kernel<<<256, 512, 0, stream>>>(
        xb, w1t, b1, counts, basep, tlist, task1, ntasks, &tickets[0], Hb);
    ffn2_kernel<<<256, 512, 0, stream>>>(
        Hb, w2t, b2, counts, basep, tlist, plist, task2, ntasks, &tickets[1], out);
}

// Round 8
// 535.601 us; speedup vs baseline: 1.0112x; 1.0112x over previous
//
#include <hip/hip_runtime.h>
#include <hip/hip_bf16.h>

// Problem constants
#define T_TOKENS 4096      // B*S
#define DIM      1024
#define HID      4096
#define NE       8
#define CAP      4096      // max tokens per expert
#define SPLITS   2         // split-K factor for ffn2
#define KSP      (HID / SPLITS)   // 2048

typedef __attribute__((ext_vector_type(8))) short  bf16x8;
typedef __attribute__((ext_vector_type(4))) float  f32x4;
typedef __attribute__((ext_vector_type(4))) ushort u16x4;

__device__ static inline ushort f2bf(float f) {
    __hip_bfloat16 h = __float2bfloat16(f);
    return *(ushort*)&h;
}

// async global -> LDS, 16 bytes per lane. LDS dest = wave-uniform base +
// lane*16 (linear). Swizzle applied on the GLOBAL source address.
__device__ static inline void gll16(const void* g, void* l) {
    __builtin_amdgcn_global_load_lds(
        (const __attribute__((address_space(1))) void*)g,
        (__attribute__((address_space(3))) void*)l,
        16, 0, 0);
}

#define MFMA16(a, b, c) __builtin_amdgcn_mfma_f32_16x16x32_bf16((a), (b), (c), 0, 0, 0)

// ---------------------------------------------------------------------------
// Gate: logits -> top2 -> softmax -> per-expert token lists; also x -> bf16.
// ---------------------------------------------------------------------------
__global__ __launch_bounds__(64) void gate_kernel(
    const float* __restrict__ x, const float* __restrict__ gw,
    const float* __restrict__ gb, __hip_bfloat16* __restrict__ xb,
    int* __restrict__ counts, int* __restrict__ tlist, float* __restrict__ plist)
{
    const int tok = blockIdx.x;
    const int l   = threadIdx.x;
    const float* xr = x + (size_t)tok * DIM;

    float part[NE];
#pragma unroll
    for (int e = 0; e < NE; e++) part[e] = 0.f;

#pragma unroll
    for (int i = 0; i < DIM / 64; i++) {
        int d = i * 64 + l;
        float xv = xr[d];
        xb[(size_t)tok * DIM + d] = __float2bfloat16(xv);
        const float4* g4 = (const float4*)(gw + (size_t)d * NE);
        float4 a = g4[0], b = g4[1];
        part[0] += xv * a.x; part[1] += xv * a.y;
        part[2] += xv * a.z; part[3] += xv * a.w;
        part[4] += xv * b.x; part[5] += xv * b.y;
        part[6] += xv * b.z; part[7] += xv * b.w;
    }
#pragma unroll
    for (int off = 32; off > 0; off >>= 1) {
#pragma unroll
        for (int e = 0; e < NE; e++) part[e] += __shfl_xor(part[e], off, 64);
    }
    if (l == 0) {
        float lg[NE];
#pragma unroll
        for (int e = 0; e < NE; e++) lg[e] = part[e] + gb[e];
        int i0 = 0;
#pragma unroll
        for (int e = 1; e < NE; e++) if (lg[e] > lg[i0]) i0 = e;   // lowest idx on tie
        int i1 = (i0 == 0) ? 1 : 0;
#pragma unroll
        for (int e = 0; e < NE; e++) if (e != i0 && lg[e] > lg[i1]) i1 = e;
        float t  = expf(lg[i1] - lg[i0]);
        float p0 = 1.f / (1.f + t);
        float p1 = t / (1.f + t);
        int pos0 = atomicAdd(&counts[i0], 1);
        tlist[i0 * CAP + pos0] = tok; plist[i0 * CAP + pos0] = p0;
        int pos1 = atomicAdd(&counts[i1], 1);
        tlist[i1 * CAP + pos1] = tok; plist[i1 * CAP + pos1] = p1;
    }
}

__global__ void finalize_kernel(const int* __restrict__ counts, int* __restrict__ base)
{
    if (threadIdx.x == 0) {
        int acc = 0;
        for (int e = 0; e < NE; e++) { base[e] = acc; acc += counts[e]; }
        base[NE] = acc;
    }
}

// ---------------------------------------------------------------------------
// Transpose + f32->bf16 convert:  in [E][K][N] f32  ->  out [E][N][K] bf16
// ---------------------------------------------------------------------------
__global__ __launch_bounds__(256) void transpose_cvt64(
    const float* __restrict__ in, __hip_bfloat16* __restrict__ outp, int K, int N)
{
    __shared__ ushort tile[64][68];
    const int e  = blockIdx.z;
    const float* src = in + (size_t)e * K * N;
    ushort* dst = (ushort*)outp + (size_t)e * K * N;
    const int k0 = blockIdx.y * 64, n0 = blockIdx.x * 64;
    const int tid = threadIdx.x;

    const int rn4 = (tid & 15) * 4;
    const int rk  = tid >> 4;
#pragma unroll
    for (int p = 0; p < 4; p++) {
        int k = rk + p * 16;
        float4 v = *(const float4*)&src[(size_t)(k0 + k) * N + n0 + rn4];
        tile[k][rn4 + 0] = f2bf(v.x);
        tile[k][rn4 + 1] = f2bf(v.y);
        tile[k][rn4 + 2] = f2bf(v.z);
        tile[k][rn4 + 3] = f2bf(v.w);
    }
    __syncthreads();
    const int wk4 = (tid & 15) * 4;
    const int wn  = tid >> 4;
#pragma unroll
    for (int p = 0; p < 4; p++) {
        int n = wn + p * 16;
        u16x4 u;
        u[0] = tile[wk4 + 0][n];
        u[1] = tile[wk4 + 1][n];
        u[2] = tile[wk4 + 2][n];
        u[3] = tile[wk4 + 3][n];
        *(u16x4*)&dst[(size_t)(n0 + n) * K + k0 + wk4] = u;
    }
}

// ===========================================================================
// 256x256 8-phase grouped GEMM core (BM=BN=256, BK=64, 8 waves 2Mx4N).
// LDS 128 KiB; slot interior [256 rows][4 chunks of 8 bf16], chunk xor-swz
// by (row>>1)&3 (measured 0 bank conflicts). Pipeline: compute tile t while
// t+1 staged and t+2 arriving; one counted vmcnt(6) per tile.
// ===========================================================================

#define AOFFc(d,s) (((d)*2+(s))*8192)
#define BOFFc(d,s) (32768 + ((d)*2+(s))*8192)

#define MFMA_CL(nj0, nj1)                                                    \
    _Pragma("unroll")                                                        \
    for (int mi = 0; mi < 8; mi++) {                                         \
        acc[mi][nj0] = MFMA16(af[mi], bf##nj0, acc[mi][nj0]);                \
        acc[mi][nj1] = MFMA16(af[mi], bf##nj1, acc[mi][nj1]);                \
    }

#define GEMM_CORE(NT, srcA0, srcA1, srcB0, srcB1)                            \
    f32x4 acc[8][4];                                                         \
    _Pragma("unroll")                                                        \
    for (int i = 0; i < 8; i++)                                              \
        _Pragma("unroll")                                                    \
        for (int j = 0; j < 4; j++) acc[i][j] = (f32x4){0.f,0.f,0.f,0.f};    \
    const int a0 = (wr * 128 + lm) * 32 + rch;                               \
    const int b0 = (wc * 64 + lm) * 32 + rch;                                \
    gll16(srcA0,      &lds[AOFFc(0,0) + w*512]);                             \
    gll16(srcA1,      &lds[AOFFc(0,0) + 4096 + w*512]);                      \
    gll16(srcB0,      &lds[BOFFc(0,0) + w*512]);                             \
    gll16(srcB1,      &lds[BOFFc(0,0) + 4096 + w*512]);                      \
    gll16(srcA0 + 32, &lds[AOFFc(0,1) + w*512]);                             \
    gll16(srcA1 + 32, &lds[AOFFc(0,1) + 4096 + w*512]);                      \
    gll16(srcB0 + 32, &lds[BOFFc(0,1) + w*512]);                             \
    gll16(srcB1 + 32, &lds[BOFFc(0,1) + 4096 + w*512]);                      \
    asm volatile("s_waitcnt vmcnt(4)" ::: "memory");                         \
    gll16(srcA0 + 64, &lds[AOFFc(1,0) + w*512]);                             \
    gll16(srcA1 + 64, &lds[AOFFc(1,0) + 4096 + w*512]);                      \
    gll16(srcB0 + 64, &lds[BOFFc(1,0) + w*512]);                             \
    gll16(srcB1 + 64, &lds[BOFFc(1,0) + 4096 + w*512]);                      \
    gll16(srcA0 + 96, &lds[AOFFc(1,1) + w*512]);                             \
    gll16(srcA1 + 96, &lds[AOFFc(1,1) + 4096 + w*512]);                      \
    asm volatile("s_waitcnt vmcnt(6)" ::: "memory");                         \
    __builtin_amdgcn_s_barrier();                                            \
    _Pragma("unroll 1")                                                      \
    for (int t = 0; t < NT; t++) {                                           \
        const int d   = t & 1;                                               \
        const int aof  = d * 16384,        bof  = 32768 + d * 16384;         \
        const int bofN = 32768 + (d^1) * 16384;                              \
        bf16x8 af[8]; bf16x8 bf0, bf1, bf2, bf3;                             \
        _Pragma("unroll")                                                    \
        for (int mi = 0; mi < 8; mi++)                                       \
            af[mi] = *(const bf16x8*)&lds[aof + a0 + mi*512];                \
        bf0 = *(const bf16x8*)&lds[bof + b0];                                \
        bf1 = *(const bf16x8*)&lds[bof + b0 + 512];                          \
        if (t + 1 < NT) {                                                    \
            size_t ko = (size_t)(t+1)*64 + 32;                               \
            gll16(srcB0 + ko, &lds[bofN + 8192 + w*512]);                    \
            gll16(srcB1 + ko, &lds[bofN + 8192 + 4096 + w*512]);             \
        }                                                                    \
        __builtin_amdgcn_s_barrier();                                        \
        __builtin_amdgcn_s_setprio(1);                                       \
        MFMA_CL(0, 1)                                                        \
        __builtin_amdgcn_s_setprio(0);                                       \
        __builtin_amdgcn_s_barrier();                                        \
        bf2 = *(const bf16x8*)&lds[bof + b0 + 1024];                         \
        bf3 = *(const bf16x8*)&lds[bof + b0 + 1536];                         \
        if (t + 2 < NT) {                                                    \
            size_t ko = (size_t)(t+2)*64;                                    \
            gll16(srcA0 + ko, &lds[aof + w*512]);                            \
            gll16(srcA1 + ko, &lds[aof + 4096 + w*512]);                     \
        }                                                                    \
        __builtin_amdgcn_s_barrier();                                        \
        __builtin_amdgcn_s_setprio(1);                                       \
        MFMA_CL(2, 3)                                                        \
        __builtin_amdgcn_s_setprio(0);                                       \
        __builtin_amdgcn_s_barrier();                                        \
        _Pragma("unroll")                                                    \
        for (int mi = 0; mi < 8; mi++)                                       \
            af[mi] = *(const bf16x8*)&lds[aof + 8192 + a0 + mi*512];         \
        bf0 = *(const bf16x8*)&lds[bof + 8192 + b0];                         \
        bf1 = *(const bf16x8*)&lds[bof + 8192 + b0 + 512];                   \
        if (t + 2 < NT) {                                                    \
            size_t ko = (size_t)(t+2)*64;                                    \
            gll16(srcB0 + ko, &lds[bof + w*512]);                            \
            gll16(srcB1 + ko, &lds[bof + 4096 + w*512]);                     \
        }                                                                    \
        __builtin_amdgcn_s_barrier();                                        \
        __builtin_amdgcn_s_setprio(1);                                       \
        MFMA_CL(0, 1)                                                        \
        __builtin_amdgcn_s_setprio(0);                                       \
        __builtin_amdgcn_s_barrier();                                        \
        bf2 = *(const bf16x8*)&lds[bof + 8192 + b0 + 1024];                  \
        bf3 = *(const bf16x8*)&lds[bof + 8192 + b0 + 1536];                  \
        if (t + 2 < NT) {                                                    \
            size_t ko = (size_t)(t+2)*64 + 32;                               \
            gll16(srcA0 + ko, &lds[aof + 8192 + w*512]);                     \
            gll16(srcA1 + ko, &lds[aof + 8192 + 4096 + w*512]);              \
        }                                                                    \
        __builtin_amdgcn_s_barrier();                                        \
        __builtin_amdgcn_s_setprio(1);                                       \
        MFMA_CL(2, 3)                                                        \
        __builtin_amdgcn_s_setprio(0);                                       \
        if (t < NT - 2) { asm volatile("s_waitcnt vmcnt(6)" ::: "memory"); } \
        else            { asm volatile("s_waitcnt vmcnt(0)" ::: "memory"); } \
        __builtin_amdgcn_s_barrier();                                        \
    }

// ---------------------------------------------------------------------------
// FFN pass 1 (XCD-pinned persistent):  H = gelu( gather(xb) @ w1t^T + b1 )
// 256 blocks (1/CU). Expert e = blockIdx&7 -> XCD e (round-robin dispatch),
// so each XCD's L2 only ever sees ONE expert's w1t/xb/H slices. Task stride
// 32 over i=rb*16+cb keeps cb FIXED per CU -> B panel (0.5 MB) stays in L2
// and is shared by the 2 CUs covering that cb.
// ---------------------------------------------------------------------------
__global__ __launch_bounds__(512, 1) void ffn1_kernel(
    const __hip_bfloat16* __restrict__ xb, const __hip_bfloat16* __restrict__ w1t,
    const float* __restrict__ b1, const int* __restrict__ counts,
    const int* __restrict__ base, const int* __restrict__ tlist,
    __hip_bfloat16* __restrict__ H)
{
    __shared__ __align__(16) ushort lds[65536];   // 128 KiB

    const int e  = blockIdx.x & 7;        // expert == XCD
    const int cu = blockIdx.x >> 3;       // 0..31 within XCD
    const int ne = counts[e];
    const int tc = (ne + 255) >> 8;       // rb tiles for this expert
    const int ntask = tc * 16;

    const int tid = threadIdx.x;
    const int l = tid & 63, w = tid >> 6;
    const int wr = w >> 2, wc = w & 3;
    const int lm = l & 15, kg = l >> 4;
    const int rch = (kg ^ ((lm >> 1) & 3)) * 8;
    const int srow = tid >> 2;                    // 0..127
    const int sch  = tid & 3;
    const int sc0  = (sch ^ ((srow >> 1) & 3)) * 8;
    const int hb = base[e];

    for (int i = cu; i < ntask; i += 32) {
        const int rb = i >> 4, cb = i & 15;   // stride 32 => cb fixed per CU
        __syncthreads();

        const int rA0g = rb * 256 + srow;
        const int rA1g = rA0g + 128;
        const int tok0 = tlist[e * CAP + (rA0g < ne ? rA0g : ne - 1)];
        const int tok1 = tlist[e * CAP + (rA1g < ne ? rA1g : ne - 1)];
        const ushort* srcA0 = (const ushort*)xb + (size_t)tok0 * DIM + sc0;
        const ushort* srcA1 = (const ushort*)xb + (size_t)tok1 * DIM + sc0;
        const ushort* srcB0 = (const ushort*)w1t + ((size_t)e * HID + cb * 256 + srow) * DIM + sc0;
        const ushort* srcB1 = srcB0 + (size_t)128 * DIM;

        GEMM_CORE(16, srcA0, srcA1, srcB0, srcB1)

        // epilogue: bias + exact GELU -> bf16 H (grouped rows)
#pragma unroll
        for (int nj = 0; nj < 4; nj++) {
            int col = cb * 256 + wc * 64 + nj * 16 + lm;
            float bias = b1[e * HID + col];
#pragma unroll
            for (int mi = 0; mi < 8; mi++) {
#pragma unroll
                for (int jj = 0; jj < 4; jj++) {
                    int r = rb * 256 + wr * 128 + mi * 16 + kg * 4 + jj;
                    if (r < ne) {
                        float vv = acc[mi][nj][jj] + bias;
                        vv = 0.5f * vv * (1.0f + erff(vv * 0.70710678118654752f));
                        H[(size_t)(hb + r) * HID + col] = __float2bfloat16(vv);
                    }
                }
            }
        }
    }
}

// ---------------------------------------------------------------------------
// FFN pass 2 (XCD-pinned persistent, split-K=2):
//   out[token] += prob * ( H @ w2t^T + b2 )
// Stride 32 over i=rb*8+cb*2+sp keeps (cb,sp) FIXED per CU -> 1 MB B panel
// L2-resident, shared by the 4 CUs covering that (cb,sp).
// ---------------------------------------------------------------------------
__global__ __launch_bounds__(512, 1) void ffn2_kernel(
    const __hip_bfloat16* __restrict__ H, const __hip_bfloat16* __restrict__ w2t,
    const float* __restrict__ b2, const int* __restrict__ counts,
    const int* __restrict__ base, const int* __restrict__ tlist,
    const float* __restrict__ plist, float* __restrict__ out)
{
    __shared__ __align__(16) ushort lds[65536];   // 128 KiB

    const int e  = blockIdx.x & 7;        // expert == XCD
    const int cu = blockIdx.x >> 3;       // 0..31 within XCD
    const int ne = counts[e];
    const int tc = (ne + 255) >> 8;
    const int ntask = tc * 8;
    const int hb = base[e];

    const int tid = threadIdx.x;
    const int l = tid & 63, w = tid >> 6;
    const int wr = w >> 2, wc = w & 3;
    const int lm = l & 15, kg = l >> 4;
    const int rch = (kg ^ ((lm >> 1) & 3)) * 8;
    const int srow = tid >> 2;
    const int sch  = tid & 3;
    const int sc0  = (sch ^ ((srow >> 1) & 3)) * 8;

    for (int i = cu; i < ntask; i += 32) {
        const int rb = i >> 3;
        const int cb = (i >> 1) & 3, sp = i & 1;  // fixed per CU
        __syncthreads();

        const int rA0g = rb * 256 + srow;
        const int rA1g = rA0g + 128;
        const int hr0  = hb + (rA0g < ne ? rA0g : ne - 1);
        const int hr1  = hb + (rA1g < ne ? rA1g : ne - 1);
        const size_t ko0 = (size_t)sp * KSP;
        const ushort* srcA0 = (const ushort*)H + (size_t)hr0 * HID + ko0 + sc0;
        const ushort* srcA1 = (const ushort*)H + (size_t)hr1 * HID + ko0 + sc0;
        const ushort* srcB0 = (const ushort*)w2t + ((size_t)e * DIM + cb * 256 + srow) * HID + ko0 + sc0;
        const ushort* srcB1 = srcB0 + (size_t)128 * HID;

        GEMM_CORE(32, srcA0, srcA1, srcB0, srcB1)

        // epilogue: prob-weighted atomic scatter to out (bias only on split 0)
#pragma unroll
        for (int mi = 0; mi < 8; mi++) {
#pragma unroll
            for (int jj = 0; jj < 4; jj++) {
                int r = rb * 256 + wr * 128 + mi * 16 + kg * 4 + jj;
                if (r < ne) {
                    int tok = tlist[e * CAP + r];
                    float p = plist[e * CAP + r];
                    float* orow = out + (size_t)tok * DIM;
#pragma unroll
                    for (int nj = 0; nj < 4; nj++) {
                        int col = cb * 256 + wc * 64 + nj * 16 + lm;
                        float vv = acc[mi][nj][jj];
                        if (sp == 0) vv += b2[e * DIM + col];
                        unsafeAtomicAdd(&orow[col], vv * p);
                    }
                }
            }
        }
    }
}

// ---------------------------------------------------------------------------
extern "C" void kernel_launch(void* const* d_in, const int* in_sizes, int n_in,
                              void* d_out, int out_size, void* d_ws, size_t ws_size,
                              hipStream_t stream)
{
    const float* x  = (const float*)d_in[0];
    const float* gw = (const float*)d_in[1];
    const float* gb = (const float*)d_in[2];
    const float* w1 = (const float*)d_in[3];
    const float* b1 = (const float*)d_in[4];
    const float* w2 = (const float*)d_in[5];
    const float* b2 = (const float*)d_in[6];
    float* out = (float*)d_out;

    // workspace carve (bytes)
    char* ws = (char*)d_ws;
    __hip_bfloat16* w1t = (__hip_bfloat16*)(ws);                    // 67108864
    __hip_bfloat16* w2t = (__hip_bfloat16*)(ws + 67108864);         // 67108864
    __hip_bfloat16* Hb  = (__hip_bfloat16*)(ws + 134217728);        // 67108864
    __hip_bfloat16* xb  = (__hip_bfloat16*)(ws + 201326592);        // 8388608
    int*   tlist  = (int*)  (ws + 209715200);                       // 131072
    float* plist  = (float*)(ws + 209846272);                       // 131072
    int*   counts = (int*)  (ws + 209977344);                       // 64
    int*   basep  = (int*)  (ws + 209977408);                       // 64

    hipMemsetAsync(out, 0, (size_t)T_TOKENS * DIM * sizeof(float), stream);
    hipMemsetAsync(counts, 0, 64, stream);

    gate_kernel<<<T_TOKENS, 64, 0, stream>>>(x, gw, gb, xb, counts, tlist, plist);
    finalize_kernel<<<1, 64, 0, stream>>>(counts, basep);

    transpose_cvt64<<<dim3(HID / 64, DIM / 64, NE), 256, 0, stream>>>(w1, w1t, DIM, HID);
    transpose_cvt64<<<dim3(DIM / 64, HID / 64, NE), 256, 0, stream>>>(w2, w2t, HID, DIM);

    // XCD-pinned persistent grids: 1 block per CU, expert = blockIdx & 7
    ffn1_kernel<<<256, 512, 0, stream>>>(
        xb, w1t, b1, counts, basep, tlist, Hb);
    ffn2_kernel<<<256, 512, 0, stream>>>(
        Hb, w2t, b2, counts, basep, tlist, plist, out);
}